// Round 7
// baseline (285.710 us; speedup 1.0000x reference)
//
#include <hip/hip_runtime.h>
#include <hip/hip_bf16.h>

// FullAttention fwd, B=4 L=S=2048 H=8 E=D=64, fp32 in/out.
// Round 7: barrier-free, LDS-free main loop. Waves partition s (32-chunk each)
// and share all 64 q of the block, so K/V have NO cross-wave reuse -> LDS
// staging was pure coalescing overhead. Kc [bh][s][e] / Vt [bh][d][s] bf16
// layouts make per-wave direct global reads 64B-sector aligned. Permuted-K QK
// trick (pi0(m)=8*(m>>2)+(m&3)) keeps PV at full rate with P in registers.
// LDS only in epilogue (cross-wave O/l reduce). launch_bounds(256,4): 1024
// blocks = exactly 4/CU, one clean generation (R6's 3/CU left a 256-block
// tail at 1/CU costing ~50% of steady-state). Register budget ~125 unified
// (oacc 64 + qfrag 16 + kf 16 + vf 16 + misc) fits the 128 cap without the
// DMA addr arrays R6 carried.

#define BNUM 4
#define LLEN 2048
#define SLEN 2048
#define HNUM 8
#define EDIM 64

typedef __attribute__((ext_vector_type(8))) short bf16x8;
typedef __attribute__((ext_vector_type(4))) float f32x4;

__device__ __forceinline__ short f2bf(float f) {
    union { __hip_bfloat16 b; short s; } u;
    u.b = __float2bfloat16(f);
    return u.s;
}

// ---- pre-pass: role 0 = K repack, role 1 = V transpose ----
__global__ __launch_bounds__(256)
void prep(const float* __restrict__ Kg, const float* __restrict__ Vg,
          short* __restrict__ Kc, short* __restrict__ Vt)
{
    __shared__ short tile[EDIM][80];
    if (blockIdx.y == 0) {
        // K [b][s][h][e] fp32 -> Kc [b][h][s][e] bf16
        const int t = blockIdx.x * 256 + threadIdx.x;
        const int e8 = t & 7;
        const int tmp = t >> 3;
        const int h = tmp & 7;
        const int tmp2 = tmp >> 3;
        const int s = tmp2 & (SLEN - 1);
        const int b = tmp2 >> 11;
        const float4* src = (const float4*)(Kg + (((size_t)(b * SLEN + s) * HNUM + h) * EDIM + e8 * 8));
        float4 a = src[0], bb = src[1];
        bf16x8 o;
        o[0]=f2bf(a.x);  o[1]=f2bf(a.y);  o[2]=f2bf(a.z);  o[3]=f2bf(a.w);
        o[4]=f2bf(bb.x); o[5]=f2bf(bb.y); o[6]=f2bf(bb.z); o[7]=f2bf(bb.w);
        *(bf16x8*)(Kc + ((size_t)((b * HNUM + h) * SLEN + s) * EDIM + e8 * 8)) = o;
    } else {
        // V [b][s][h][d] fp32 -> Vt [b][h][d][s] bf16 (64x64 tile transpose)
        if (blockIdx.x >= 1024) return;
        const int x = blockIdx.x;
        const int s0 = (x & 31) * 64;
        const int bh = x >> 5;
        const int b = bh >> 3, h = bh & 7;
        {
            const int sr = threadIdx.x >> 2, dc = (threadIdx.x & 3) * 16;
            const float4* src = (const float4*)(Vg + (((size_t)(b * SLEN + s0 + sr) * HNUM + h) * EDIM + dc));
            #pragma unroll
            for (int j4 = 0; j4 < 4; ++j4) {
                float4 a = src[j4];
                tile[dc + j4*4 + 0][sr] = f2bf(a.x);
                tile[dc + j4*4 + 1][sr] = f2bf(a.y);
                tile[dc + j4*4 + 2][sr] = f2bf(a.z);
                tile[dc + j4*4 + 3][sr] = f2bf(a.w);
            }
        }
        __syncthreads();
        {
            const int dr = threadIdx.x >> 2, sc = (threadIdx.x & 3) * 16;
            short* dst = Vt + ((size_t)((b * HNUM + h) * EDIM + dr) * SLEN + s0 + sc);
            *(bf16x8*)dst       = *(const bf16x8*)&tile[dr][sc];
            *(bf16x8*)(dst + 8) = *(const bf16x8*)&tile[dr][sc + 8];
        }
    }
}

// ---- main kernel: no LDS, no barriers in the s-loop ----
__global__ __launch_bounds__(256, 4)
void fa_fwd(const float* __restrict__ Qg, const short* __restrict__ Kc,
            const short* __restrict__ Vt, float* __restrict__ Og)
{
    __shared__ float sO[64 * 68];   // padded rows (68) to soften epilogue conflicts
    __shared__ float sL[4][64];

    const int tid  = threadIdx.x;
    const int wave = tid >> 6;
    const int lane = tid & 63;
    const int m    = lane & 15;
    const int quad = lane >> 4;
    const int h = blockIdx.y, b = blockIdx.z;
    const int qbase = blockIdx.x * 64;
    const int bh = b * HNUM + h;

    const short* Kbh = Kc + (size_t)bh * SLEN * EDIM;
    const short* Vbh = Vt + (size_t)bh * EDIM * SLEN;

    // ---- Q fragments from global fp32, prescaled (B-op: B[k=e][n=q=m]) ----
    const float csc = 0.18033688011112042f;   // (1/sqrt(64)) * log2(e)
    bf16x8 qfrag[4][2];
    #pragma unroll
    for (int qt = 0; qt < 4; ++qt)
        #pragma unroll
        for (int kb = 0; kb < 2; ++kb) {
            const float* qp = Qg + ((size_t)(b * LLEN + qbase + qt * 16 + m) * HNUM + h) * EDIM
                              + kb * 32 + quad * 8;
            float4 x0 = *(const float4*)qp;
            float4 x1 = *(const float4*)(qp + 4);
            bf16x8 f;
            f[0]=f2bf(x0.x*csc); f[1]=f2bf(x0.y*csc); f[2]=f2bf(x0.z*csc); f[3]=f2bf(x0.w*csc);
            f[4]=f2bf(x1.x*csc); f[5]=f2bf(x1.y*csc); f[6]=f2bf(x1.z*csc); f[7]=f2bf(x1.w*csc);
            qfrag[qt][kb] = f;
        }

    // ---- per-lane source pointers (element offsets) ----
    // K rows permuted: pi0 = 8*(m>>2)+(m&3); lane reads rows (pi0, pi0+4) of
    // its wave's 32-s window, e-chunks quad*8 and 32+quad*8 (16B each).
    const int pi0 = 8 * (m >> 2) + (m & 3);
    const short* kp0 = Kbh + (size_t)(wave * 32 + pi0) * EDIM + quad * 8;
    const short* kp1 = kp0 + 4 * EDIM;
    // V: row d=dt*16+m, s = s0 + wave*32 + quad*8 (16B each)
    const short* vp0 = Vbh + (size_t)m * SLEN + wave * 32 + quad * 8;

    f32x4 oacc[4][4];
    #pragma unroll
    for (int i = 0; i < 4; ++i)
        #pragma unroll
        for (int j = 0; j < 4; ++j) oacc[i][j] = (f32x4){0.f, 0.f, 0.f, 0.f};
    float lsum[4] = {0.f, 0.f, 0.f, 0.f};

    for (int s0 = 0; s0 < SLEN; s0 += 128) {
        // ---- direct global loads (L2-resident; 64B-sector aligned patterns) ----
        const short* kp = kp0 + s0 * EDIM;
        const short* kq = kp1 + s0 * EDIM;
        bf16x8 kf00 = *(const bf16x8*)(kp);
        bf16x8 kf01 = *(const bf16x8*)(kp + 32);
        bf16x8 kf10 = *(const bf16x8*)(kq);
        bf16x8 kf11 = *(const bf16x8*)(kq + 32);
        const short* vp = vp0 + s0;
        bf16x8 vf0 = *(const bf16x8*)(vp);
        bf16x8 vf1 = *(const bf16x8*)(vp + 16 * SLEN);
        bf16x8 vf2 = *(const bf16x8*)(vp + 32 * SLEN);
        bf16x8 vf3 = *(const bf16x8*)(vp + 48 * SLEN);

        // ---- compute: 32 full-rate MFMAs per wave ----
        #pragma unroll
        for (int qt = 0; qt < 4; ++qt) {
            f32x4 a0 = {0.f, 0.f, 0.f, 0.f};
            f32x4 a1 = {0.f, 0.f, 0.f, 0.f};
            a0 = __builtin_amdgcn_mfma_f32_16x16x32_bf16(kf00, qfrag[qt][0], a0, 0, 0, 0);
            a0 = __builtin_amdgcn_mfma_f32_16x16x32_bf16(kf01, qfrag[qt][1], a0, 0, 0, 0);
            a1 = __builtin_amdgcn_mfma_f32_16x16x32_bf16(kf10, qfrag[qt][0], a1, 0, 0, 0);
            a1 = __builtin_amdgcn_mfma_f32_16x16x32_bf16(kf11, qfrag[qt][1], a1, 0, 0, 0);
            // a0[r] = S[s_local=8*quad+r][q=m], a1[r] = S[s_local=8*quad+4+r][q=m]
            float p0 = __builtin_amdgcn_exp2f(a0[0]);
            float p1 = __builtin_amdgcn_exp2f(a0[1]);
            float p2 = __builtin_amdgcn_exp2f(a0[2]);
            float p3 = __builtin_amdgcn_exp2f(a0[3]);
            float p4 = __builtin_amdgcn_exp2f(a1[0]);
            float p5 = __builtin_amdgcn_exp2f(a1[1]);
            float p6 = __builtin_amdgcn_exp2f(a1[2]);
            float p7 = __builtin_amdgcn_exp2f(a1[3]);
            lsum[qt] += ((p0 + p1) + (p2 + p3)) + ((p4 + p5) + (p6 + p7));
            bf16x8 pf;   // A-op of 16x16x32: A[q=m][k=s_local=quad*8+j]
            pf[0]=f2bf(p0); pf[1]=f2bf(p1); pf[2]=f2bf(p2); pf[3]=f2bf(p3);
            pf[4]=f2bf(p4); pf[5]=f2bf(p5); pf[6]=f2bf(p6); pf[7]=f2bf(p7);
            oacc[qt][0] = __builtin_amdgcn_mfma_f32_16x16x32_bf16(pf, vf0, oacc[qt][0], 0, 0, 0);
            oacc[qt][1] = __builtin_amdgcn_mfma_f32_16x16x32_bf16(pf, vf1, oacc[qt][1], 0, 0, 0);
            oacc[qt][2] = __builtin_amdgcn_mfma_f32_16x16x32_bf16(pf, vf2, oacc[qt][2], 0, 0, 0);
            oacc[qt][3] = __builtin_amdgcn_mfma_f32_16x16x32_bf16(pf, vf3, oacc[qt][3], 0, 0, 0);
        }
    }

    // ---- epilogue: reduce l and O across the 4 s-chunk waves ----
    #pragma unroll
    for (int qt = 0; qt < 4; ++qt) {
        float l = lsum[qt];
        l += __shfl_xor(l, 16);
        l += __shfl_xor(l, 32);
        if (lane < 16) sL[wave][qt * 16 + lane] = l;
    }
    __syncthreads();

    for (int w = 0; w < 4; ++w) {
        if (wave == w) {
            #pragma unroll
            for (int qt = 0; qt < 4; ++qt)
                #pragma unroll
                for (int dt = 0; dt < 4; ++dt)
                    #pragma unroll
                    for (int r = 0; r < 4; ++r) {
                        const int q = qt * 16 + quad * 4 + r;
                        const int d = dt * 16 + m;
                        if (w == 0) sO[q * 68 + d] = oacc[qt][dt][r];
                        else        sO[q * 68 + d] += oacc[qt][dt][r];
                    }
        }
        __syncthreads();
    }

    {
        const int q = tid >> 2;
        const int dcol = (tid & 3) * 16;
        const float l = sL[0][q] + sL[1][q] + sL[2][q] + sL[3][q];
        const float inv = 1.0f / l;
        float* orow = Og + ((size_t)(b * LLEN + qbase + q) * HNUM + h) * EDIM + dcol;
        #pragma unroll
        for (int j = 0; j < 4; ++j) {
            float4 v = *(const float4*)(sO + q * 68 + dcol + j * 4);
            v.x *= inv; v.y *= inv; v.z *= inv; v.w *= inv;
            *(float4*)(orow + j * 4) = v;
        }
    }
}

extern "C" void kernel_launch(void* const* d_in, const int* in_sizes, int n_in,
                              void* d_out, int out_size, void* d_ws, size_t ws_size,
                              hipStream_t stream) {
    const float* Q = (const float*)d_in[0];
    const float* K = (const float*)d_in[1];
    const float* V = (const float*)d_in[2];
    float* O = (float*)d_out;

    const size_t NE = (size_t)BNUM * LLEN * HNUM * EDIM;   // 4,194,304
    short* Kc = (short*)d_ws;
    short* Vt = Kc + NE;

    prep<<<dim3(2048, 2), dim3(256), 0, stream>>>(K, V, Kc, Vt);
    fa_fwd<<<dim3(LLEN / 64, HNUM, BNUM), dim3(256), 0, stream>>>(Q, Kc, Vt, O);
}

// Round 9
// 146.421 us; speedup vs baseline: 1.9513x; 1.9513x over previous
//
#include <hip/hip_runtime.h>
#include <hip/hip_bf16.h>

// FullAttention fwd, B=4 L=S=2048 H=8 E=D=64, fp32 in/out.
// Round 9: strict restriction of the PROVEN R6 kernel (73.5us) to 2-wave
// blocks: block = 32 q-rows x 64-s tiles, wave w owns s-window w*32. All
// staging/swizzle/read-offset formulas are R6's verbatim (wave in {0,1});
// barrier structure is R6's (read frags -> barrier1 -> DMA next -> compute
// -> barrier2, single buffer). oacc drops to 32 AGPR so the block fits
// __launch_bounds__(128,4) = 8 blocks/CU: grid 2048 = exactly one clean
// generation, killing R6's 1-block/CU tail (its measured 22% occupancy).
// Permuted-K QK trick (pi0(m)=8*(m>>2)+(m&3)) keeps PV full-rate, P in regs.

#define BNUM 4
#define LLEN 2048
#define SLEN 2048
#define HNUM 8
#define EDIM 64

typedef __attribute__((ext_vector_type(8))) short bf16x8;
typedef __attribute__((ext_vector_type(4))) float f32x4;

__device__ __forceinline__ short f2bf(float f) {
    union { __hip_bfloat16 b; short s; } u;
    u.b = __float2bfloat16(f);
    return u.s;
}

#if __has_builtin(__builtin_amdgcn_global_load_lds)
#define HAVE_GLL 1
#else
#define HAVE_GLL 0
#endif

__device__ __forceinline__ void stage16(const short* g, short* l) {
#if HAVE_GLL
    __builtin_amdgcn_global_load_lds(
        (const __attribute__((address_space(1))) void*)g,
        (__attribute__((address_space(3))) void*)l, 16, 0, 0);
#else
    *(bf16x8*)l = *(const bf16x8*)g;
#endif
}

// ---- pre-pass: role 0 = K repack, role 1 = V transpose ----
__global__ __launch_bounds__(256)
void prep(const float* __restrict__ Kg, const float* __restrict__ Vg,
          short* __restrict__ Kc, short* __restrict__ Vt)
{
    __shared__ short tile[EDIM][80];
    if (blockIdx.y == 0) {
        // K [b][s][h][e] fp32 -> Kc [b][h][s][e] bf16
        const int t = blockIdx.x * 256 + threadIdx.x;
        const int e8 = t & 7;
        const int tmp = t >> 3;
        const int h = tmp & 7;
        const int tmp2 = tmp >> 3;
        const int s = tmp2 & (SLEN - 1);
        const int b = tmp2 >> 11;
        const float4* src = (const float4*)(Kg + (((size_t)(b * SLEN + s) * HNUM + h) * EDIM + e8 * 8));
        float4 a = src[0], bb = src[1];
        bf16x8 o;
        o[0]=f2bf(a.x);  o[1]=f2bf(a.y);  o[2]=f2bf(a.z);  o[3]=f2bf(a.w);
        o[4]=f2bf(bb.x); o[5]=f2bf(bb.y); o[6]=f2bf(bb.z); o[7]=f2bf(bb.w);
        *(bf16x8*)(Kc + ((size_t)((b * HNUM + h) * SLEN + s) * EDIM + e8 * 8)) = o;
    } else {
        // V [b][s][h][d] fp32 -> Vt [b][h][d][s] bf16 (64x64 tile transpose)
        if (blockIdx.x >= 1024) return;
        const int x = blockIdx.x;
        const int s0 = (x & 31) * 64;
        const int bh = x >> 5;
        const int b = bh >> 3, h = bh & 7;
        {
            const int sr = threadIdx.x >> 2, dc = (threadIdx.x & 3) * 16;
            const float4* src = (const float4*)(Vg + (((size_t)(b * SLEN + s0 + sr) * HNUM + h) * EDIM + dc));
            #pragma unroll
            for (int j4 = 0; j4 < 4; ++j4) {
                float4 a = src[j4];
                tile[dc + j4*4 + 0][sr] = f2bf(a.x);
                tile[dc + j4*4 + 1][sr] = f2bf(a.y);
                tile[dc + j4*4 + 2][sr] = f2bf(a.z);
                tile[dc + j4*4 + 3][sr] = f2bf(a.w);
            }
        }
        __syncthreads();
        {
            const int dr = threadIdx.x >> 2, sc = (threadIdx.x & 3) * 16;
            short* dst = Vt + ((size_t)((b * HNUM + h) * EDIM + dr) * SLEN + s0 + sc);
            *(bf16x8*)dst       = *(const bf16x8*)&tile[dr][sc];
            *(bf16x8*)(dst + 8) = *(const bf16x8*)&tile[dr][sc + 8];
        }
    }
}

// ---- main kernel (R6 structure, 2 waves) ----
// LDS: K region [0:4096) shorts = 64 s-rows x 8 chunks(16B), chunk (r,c) at
// r*8 + (c ^ g(r)), g(r) = ((r>>3)&1)*4 + (r&3)   [R6's formula verbatim].
// V region [4096:8192) = 2 panels (per-wave 32-s window), panel = 64 d-rows x
// 4 chunks(16B), chunk (d,c) at d*4 + (c ^ (d&3))  [R6's formula verbatim].
__global__ __launch_bounds__(128, 4)
void fa_fwd(const float* __restrict__ Qg, const short* __restrict__ Kc,
            const short* __restrict__ Vt, float* __restrict__ Og)
{
    __shared__ short sKV[8192];   // 16 KB; reused as sO (32 x 68 f32) in epilogue
    __shared__ float sL[2][32];

    const int tid  = threadIdx.x;
    const int wave = tid >> 6;    // s-window index {0,1}
    const int lane = tid & 63;
    const int m    = lane & 15;
    const int quad = lane >> 4;
    const int h = blockIdx.y, b = blockIdx.z;
    const int qbase = blockIdx.x * 32;
    const int bh = b * HNUM + h;

    const short* Kbh = Kc + (size_t)bh * SLEN * EDIM;
    const short* Vbh = Vt + (size_t)bh * EDIM * SLEN;

    // ---- staging bases (R6 formulas; p-dependence folded into constants) ----
    const int l3 = lane >> 3;
    const int ksrcE = (wave * 32 + l3) * EDIM + ((lane & 7) ^ (l3 & 3)) * 8;        // p even
    const int ksrcO = (wave * 32 + l3) * EDIM + ((lane & 7) ^ (4 + (l3 & 3))) * 8;  // p odd
    const int vsrcB = (lane >> 2) * SLEN + wave * 32 + ((lane & 3) ^ ((lane >> 2) & 3)) * 8;
    short* kdstB = sKV + (wave * 256 + lane) * 8;
    short* vdstB = sKV + 4096 + (wave * 256 + lane) * 8;

#define STAGE_TILE(s0)                                                        \
    do {                                                                      \
        _Pragma("unroll")                                                     \
        for (int p = 0; p < 4; ++p) {                                         \
            const int ks = ((p & 1) ? ksrcO : ksrcE) + (p >> 1) * 1024 + (p & 1) * 512; \
            stage16(Kbh + (size_t)(s0) * EDIM + ks, kdstB + p * 512);         \
            stage16(Vbh + (s0) + vsrcB + p * 16 * SLEN, vdstB + p * 512);     \
        }                                                                     \
    } while (0)

    // ---- Q fragments (B-op: B[k=e=kb*32+quad*8+j][n=q=qt*16+m]), prescaled ----
    const float csc = 0.18033688011112042f;   // (1/sqrt(64)) * log2(e)
    bf16x8 qfrag[2][2];
    #pragma unroll
    for (int qt = 0; qt < 2; ++qt)
        #pragma unroll
        for (int kb = 0; kb < 2; ++kb) {
            const float* qp = Qg + ((size_t)(b * LLEN + qbase + qt * 16 + m) * HNUM + h) * EDIM
                              + kb * 32 + quad * 8;
            float4 x0 = *(const float4*)qp;
            float4 x1 = *(const float4*)(qp + 4);
            bf16x8 f;
            f[0]=f2bf(x0.x*csc); f[1]=f2bf(x0.y*csc); f[2]=f2bf(x0.z*csc); f[3]=f2bf(x0.w*csc);
            f[4]=f2bf(x1.x*csc); f[5]=f2bf(x1.y*csc); f[6]=f2bf(x1.z*csc); f[7]=f2bf(x1.w*csc);
            qfrag[qt][kb] = f;
        }

    // ---- frag read offsets (R6 formulas verbatim, wave in {0,1}) ----
    const int gk  = ((m >> 2) & 1) * 4 + (m & 3);
    const int pi0 = 8 * (m >> 2) + (m & 3);
    const int kOff00 = (wave * 32 + pi0)     * 64 + ((quad)     ^ gk) * 8;
    const int kOff01 = (wave * 32 + pi0)     * 64 + ((4 + quad) ^ gk) * 8;
    const int kOff10 = (wave * 32 + pi0 + 4) * 64 + ((quad)     ^ gk) * 8;
    const int kOff11 = (wave * 32 + pi0 + 4) * 64 + ((4 + quad) ^ gk) * 8;
    const int vOffB  = 4096 + wave * 2048 + m * 32 + ((quad ^ (m & 3)) * 8);

    f32x4 oacc[2][4];   // [qt][dt] -- 32 AGPR
    #pragma unroll
    for (int i = 0; i < 2; ++i)
        #pragma unroll
        for (int j = 0; j < 4; ++j) oacc[i][j] = (f32x4){0.f, 0.f, 0.f, 0.f};
    float lsum[2] = {0.f, 0.f};

    STAGE_TILE(0);
    __syncthreads();   // tile 0 resident

    for (int s0 = 0; s0 < SLEN; s0 += 64) {
        // ---- LDS -> registers (balanced b128, conflict-free) ----
        bf16x8 kf00 = *(const bf16x8*)(sKV + kOff00);
        bf16x8 kf01 = *(const bf16x8*)(sKV + kOff01);
        bf16x8 kf10 = *(const bf16x8*)(sKV + kOff10);
        bf16x8 kf11 = *(const bf16x8*)(sKV + kOff11);
        bf16x8 vf0 = *(const bf16x8*)(sKV + vOffB);
        bf16x8 vf1 = *(const bf16x8*)(sKV + vOffB + 512);
        bf16x8 vf2 = *(const bf16x8*)(sKV + vOffB + 1024);
        bf16x8 vf3 = *(const bf16x8*)(sKV + vOffB + 1536);

        __syncthreads();   // barrier1: both waves hold the tile in regs

        if (s0 + 64 < SLEN) STAGE_TILE(s0 + 64);   // DMA next; overlaps compute

        // ---- compute: 16 full-rate MFMAs per wave per tile ----
        #pragma unroll
        for (int qt = 0; qt < 2; ++qt) {
            f32x4 a0 = {0.f, 0.f, 0.f, 0.f};
            f32x4 a1 = {0.f, 0.f, 0.f, 0.f};
            a0 = __builtin_amdgcn_mfma_f32_16x16x32_bf16(kf00, qfrag[qt][0], a0, 0, 0, 0);
            a0 = __builtin_amdgcn_mfma_f32_16x16x32_bf16(kf01, qfrag[qt][1], a0, 0, 0, 0);
            a1 = __builtin_amdgcn_mfma_f32_16x16x32_bf16(kf10, qfrag[qt][0], a1, 0, 0, 0);
            a1 = __builtin_amdgcn_mfma_f32_16x16x32_bf16(kf11, qfrag[qt][1], a1, 0, 0, 0);
            // a0[r]=S[s_local=8*quad+r][q], a1[r]=S[s_local=8*quad+4+r][q]
            float p0 = __builtin_amdgcn_exp2f(a0[0]);
            float p1 = __builtin_amdgcn_exp2f(a0[1]);
            float p2 = __builtin_amdgcn_exp2f(a0[2]);
            float p3 = __builtin_amdgcn_exp2f(a0[3]);
            float p4 = __builtin_amdgcn_exp2f(a1[0]);
            float p5 = __builtin_amdgcn_exp2f(a1[1]);
            float p6 = __builtin_amdgcn_exp2f(a1[2]);
            float p7 = __builtin_amdgcn_exp2f(a1[3]);
            lsum[qt] += ((p0 + p1) + (p2 + p3)) + ((p4 + p5) + (p6 + p7));
            bf16x8 pf;   // A-op: A[q=m][k=s_local=quad*8+j]
            pf[0]=f2bf(p0); pf[1]=f2bf(p1); pf[2]=f2bf(p2); pf[3]=f2bf(p3);
            pf[4]=f2bf(p4); pf[5]=f2bf(p5); pf[6]=f2bf(p6); pf[7]=f2bf(p7);
            oacc[qt][0] = __builtin_amdgcn_mfma_f32_16x16x32_bf16(pf, vf0, oacc[qt][0], 0, 0, 0);
            oacc[qt][1] = __builtin_amdgcn_mfma_f32_16x16x32_bf16(pf, vf1, oacc[qt][1], 0, 0, 0);
            oacc[qt][2] = __builtin_amdgcn_mfma_f32_16x16x32_bf16(pf, vf2, oacc[qt][2], 0, 0, 0);
            oacc[qt][3] = __builtin_amdgcn_mfma_f32_16x16x32_bf16(pf, vf3, oacc[qt][3], 0, 0, 0);
        }

        __syncthreads();   // barrier2: DMA drained after compute; next tile ready
    }

    // ---- epilogue: 2-way (wave) l and O reduce ----
    #pragma unroll
    for (int qt = 0; qt < 2; ++qt) {
        float l = lsum[qt];
        l += __shfl_xor(l, 16);
        l += __shfl_xor(l, 32);
        if (lane < 16) sL[wave][qt * 16 + lane] = l;
    }
    __syncthreads();

    float* sO = (float*)sKV;   // 32 rows x 68 floats = 8704 B
    if (wave == 0) {
        #pragma unroll
        for (int qt = 0; qt < 2; ++qt)
            #pragma unroll
            for (int dt = 0; dt < 4; ++dt)
                #pragma unroll
                for (int r = 0; r < 4; ++r)
                    sO[(qt * 16 + quad * 4 + r) * 68 + dt * 16 + m] = oacc[qt][dt][r];
    }
    __syncthreads();
    if (wave == 1) {
        #pragma unroll
        for (int qt = 0; qt < 2; ++qt)
            #pragma unroll
            for (int dt = 0; dt < 4; ++dt)
                #pragma unroll
                for (int r = 0; r < 4; ++r)
                    sO[(qt * 16 + quad * 4 + r) * 68 + dt * 16 + m] += oacc[qt][dt][r];
    }
    __syncthreads();

    {
        const int q = tid >> 2;            // [0,32)
        const int dcol = (tid & 3) * 16;
        const float l = sL[0][q] + sL[1][q];
        const float inv = 1.0f / l;
        float* orow = Og + ((size_t)(b * LLEN + qbase + q) * HNUM + h) * EDIM + dcol;
        #pragma unroll
        for (int j = 0; j < 4; ++j) {
            float4 v = *(const float4*)(sO + q * 68 + dcol + j * 4);
            v.x *= inv; v.y *= inv; v.z *= inv; v.w *= inv;
            *(float4*)(orow + j * 4) = v;
        }
    }
}

extern "C" void kernel_launch(void* const* d_in, const int* in_sizes, int n_in,
                              void* d_out, int out_size, void* d_ws, size_t ws_size,
                              hipStream_t stream) {
    const float* Q = (const float*)d_in[0];
    const float* K = (const float*)d_in[1];
    const float* V = (const float*)d_in[2];
    float* O = (float*)d_out;

    const size_t NE = (size_t)BNUM * LLEN * HNUM * EDIM;   // 4,194,304
    short* Kc = (short*)d_ws;
    short* Vt = Kc + NE;

    prep<<<dim3(2048, 2), dim3(256), 0, stream>>>(K, V, Kc, Vt);
    fa_fwd<<<dim3(LLEN / 32, HNUM, BNUM), dim3(128), 0, stream>>>(Q, Kc, Vt, O);
}